// Round 1
// baseline (226.331 us; speedup 1.0000x reference)
//
#include <hip/hip_runtime.h>

// FWHT over last dim (4096) of [8192, 4096] fp32, normalized by 1/64.
// H_4096 = H_16 (x) H_16 (x) H_16 : three register-local FWHT-16 passes with
// LDS transposes in between. One block of 256 threads per row.

#define N        4096
#define THREADS  256
#define A_STR    20    // LDS stride for i1 digit (mult of 4 for float4 align; gcd(20,32)=4 -> uniform banks)
#define B_STR    328   // LDS stride for i2 digit (>= 20*15+16; 328 % 32 == 8 -> 2-way (free) aliasing)
#define LDS_FLOATS (B_STR * 15 + A_STR * 15 + 16)   // 5236 floats = 20944 B

__device__ __forceinline__ void fwht16(float v[16]) {
    // In-place 16-point FWHT, stages LSB->MSB (stride 1,2,4,8).
    // Same addition tree as the reference's recursive butterfly.
#pragma unroll
    for (int s = 1; s < 16; s <<= 1) {
#pragma unroll
        for (int k = 0; k < 16; k++) {
            if ((k & s) == 0) {
                float a = v[k];
                float b = v[k + s];
                v[k]     = a + b;
                v[k + s] = a - b;
            }
        }
    }
}

__global__ __launch_bounds__(THREADS)
void FWHT_83476984365427_kernel(const float* __restrict__ x,
                                float* __restrict__ out,
                                int nrows) {
    __shared__ float lds[LDS_FLOATS];

    const int row = blockIdx.x;
    if (row >= nrows) return;

    const float* __restrict__ xr  = x   + (size_t)row * N;
    float* __restrict__       otr = out + (size_t)row * N;
    const int t = threadIdx.x;

    float v[16];

    // ---- Phase 1: bits 0-3 (i0 digit). Thread t holds x[t*16 + j], j=0..15.
    // Coalesced float4 loads: lane-consecutive 16B chunks within each c.
    {
        const float4* xv = (const float4*)xr + (size_t)t * 4;
#pragma unroll
        for (int c = 0; c < 4; c++) {
            float4 f = xv[c];
            v[4 * c + 0] = f.x;
            v[4 * c + 1] = f.y;
            v[4 * c + 2] = f.z;
            v[4 * c + 3] = f.w;
        }
    }
    fwht16(v);

    // Write to LDS at addr = i0 + A_STR*i1 + B_STR*i2, where t = i2*16 + i1.
    {
        const int i2 = t >> 4;
        const int i1 = t & 15;
        float* dst = &lds[A_STR * i1 + B_STR * i2];   // 16B aligned (both strides mult of 4 floats)
#pragma unroll
        for (int c = 0; c < 4; c++) {
            float4 f;
            f.x = v[4 * c + 0];
            f.y = v[4 * c + 1];
            f.z = v[4 * c + 2];
            f.w = v[4 * c + 3];
            *(float4*)(dst + 4 * c) = f;
        }
    }
    __syncthreads();

    // ---- Phase 2: bits 4-7 (i1 digit). Thread t = i2*16 + i0.
    {
        const int i2 = t >> 4;
        const int i0 = t & 15;
        const int base = i0 + B_STR * i2;
#pragma unroll
        for (int k = 0; k < 16; k++) v[k] = lds[base + A_STR * k];
        fwht16(v);
        // Same thread owns these 16 addresses exclusively -> no barrier needed before write.
#pragma unroll
        for (int k = 0; k < 16; k++) lds[base + A_STR * k] = v[k];
    }
    __syncthreads();

    // ---- Phase 3: bits 8-11 (i2 digit). Thread t = i1*16 + i0.
    {
        const int i1 = t >> 4;
        const int i0 = t & 15;
        const int base = i0 + A_STR * i1;
#pragma unroll
        for (int k = 0; k < 16; k++) v[k] = lds[base + B_STR * k];
        fwht16(v);
        const float scale = 1.0f / 64.0f;   // 1/sqrt(4096), exact
        // out index = i2*256 + i1*16 + i0 = i2*256 + t -> lane-consecutive, coalesced.
#pragma unroll
        for (int k = 0; k < 16; k++) otr[k * 256 + t] = v[k] * scale;
    }
}

extern "C" void kernel_launch(void* const* d_in, const int* in_sizes, int n_in,
                              void* d_out, int out_size, void* d_ws, size_t ws_size,
                              hipStream_t stream) {
    (void)n_in; (void)d_ws; (void)ws_size; (void)out_size;
    const float* x = (const float*)d_in[0];
    float* out = (float*)d_out;
    const int nrows = in_sizes[0] / N;
    dim3 grid(nrows);
    dim3 block(THREADS);
    FWHT_83476984365427_kernel<<<grid, block, 0, stream>>>(x, out, nrows);
}